// Round 1
// baseline (60.087 us; speedup 1.0000x reference)
//
#include <hip/hip_runtime.h>

// VoxelQueryAndGrouping — MI355X (gfx950)
// One 64-lane wave per query. Phase A: ballot-ordered neighbor scan (125
// voxels, first NSAMPLE valid kept in scan order). Phase B: coalesced
// gather/transpose of features (M,C,16) and xyz (M,3,16) + empty flag.

constexpr int ZG = 21;
constexpr int YG = 400;
constexpr int XG = 352;
constexpr int NS = 16;   // NSAMPLE
constexpr int CF = 32;   // feature channels
constexpr float R2 = 64.0f; // RADIUS^2

__global__ __launch_bounds__(256) void vqg_kernel(
    const int*   __restrict__ new_coords,     // (M,4) [b,z,y,x]
    const float* __restrict__ xyz,            // (N,3)
    const int*   __restrict__ xyz_batch_cnt,  // (B,)
    const float* __restrict__ new_xyz,        // (M,3)
    const float* __restrict__ features,       // (N,CF)
    const int*   __restrict__ v2p,            // (B,ZG,YG,XG)
    float* __restrict__ out_feat,             // (M,CF,NS)
    float* __restrict__ out_xyz,              // (M,3,NS)
    float* __restrict__ out_empty,            // (M,)
    int M)
{
    const int lane = threadIdx.x & 63;
    const int wid  = threadIdx.x >> 6;
    const int m    = blockIdx.x * 4 + wid;
    __shared__ int sg[4][NS];

    const bool active = (m < M);
    int cnt  = 0;
    int boff = 0;

    if (active) {
        const int4 qc = *reinterpret_cast<const int4*>(new_coords + (size_t)m * 4);
        const int b = qc.x, zc = qc.y, yc = qc.z, xc = qc.w;
        const float qx = new_xyz[m * 3 + 0];
        const float qy = new_xyz[m * 3 + 1];
        const float qz = new_xyz[m * 3 + 2];
        for (int i = 0; i < b; ++i) boff += xyz_batch_cnt[i];
        const int* __restrict__ gb = v2p + (size_t)b * (ZG * YG * XG);

        // Neighbor scan order must match reference: dz slowest, dx fastest.
        #pragma unroll
        for (int pass = 0; pass < 2; ++pass) {
            const int n = pass * 64 + lane;
            int  pidx  = -1;
            bool valid = false;
            if (n < 125) {
                const int dz = n / 25 - 2;
                const int dy = (n / 5) % 5 - 2;
                const int dx = n % 5 - 2;
                const int z = zc + dz, y = yc + dy, x = xc + dx;
                if ((unsigned)z < (unsigned)ZG && (unsigned)y < (unsigned)YG &&
                    (unsigned)x < (unsigned)XG) {
                    pidx = gb[((size_t)z * YG + y) * XG + x];
                    if (pidx >= 0) {
                        // no-FMA distance to bit-match numpy's ((dx2+dy2)+dz2)
                        const float ddx = xyz[(size_t)pidx * 3 + 0] - qx;
                        const float ddy = xyz[(size_t)pidx * 3 + 1] - qy;
                        const float ddz = xyz[(size_t)pidx * 3 + 2] - qz;
                        const float d2 = __fadd_rn(
                            __fadd_rn(__fmul_rn(ddx, ddx), __fmul_rn(ddy, ddy)),
                            __fmul_rn(ddz, ddz));
                        valid = d2 < R2;
                    }
                }
            }
            const unsigned long long bal = __ballot(valid);
            const int pos = cnt + (int)__popcll(bal & ((1ull << lane) - 1ull));
            if (valid && pos < NS) sg[wid][pos] = pidx;
            cnt += (int)__popcll(bal);
            if (cnt >= NS) break;  // wave-uniform; slots are full
        }
    }
    __syncthreads();

    if (active && lane < NS) {
        int g;
        if (cnt == 0) {
            g = boff;                       // empty: gidx = xyz_offs[b]
        } else {
            const int first = sg[wid][0];
            const int c = cnt < NS ? cnt : NS;
            g = (lane < c) ? sg[wid][lane] : first;
        }
        sg[wid][lane] = g;
    }
    __syncthreads();

    if (active) {
        // grouped_xyz (M,3,NS): 48 floats, one per lane
        if (lane < 48) {
            const int s = lane & 15;
            const int d = lane >> 4;
            out_xyz[(size_t)m * 48 + d * 16 + s] =
                xyz[(size_t)sg[wid][s] * 3 + d];
        }
        if (lane == 0) out_empty[m] = (cnt == 0) ? 1.0f : 0.0f;

        // grouped_features (M,CF,NS): 512 floats, float4 per lane x2 iters.
        // f = k*256 + 4*lane; c = f>>4, s0 = f&15 (s0 in {0,4,8,12}).
        float* __restrict__ of = out_feat + (size_t)m * (CF * NS);
        #pragma unroll
        for (int k = 0; k < 2; ++k) {
            const int f0 = k * 256 + lane * 4;
            const int c  = f0 >> 4;
            const int s0 = f0 & 15;
            float4 v;
            v.x = features[(size_t)sg[wid][s0 + 0] * CF + c];
            v.y = features[(size_t)sg[wid][s0 + 1] * CF + c];
            v.z = features[(size_t)sg[wid][s0 + 2] * CF + c];
            v.w = features[(size_t)sg[wid][s0 + 3] * CF + c];
            *reinterpret_cast<float4*>(of + f0) = v;
        }
    }
}

extern "C" void kernel_launch(void* const* d_in, const int* in_sizes, int n_in,
                              void* d_out, int out_size, void* d_ws, size_t ws_size,
                              hipStream_t stream) {
    const int*   new_coords    = (const int*)d_in[0];
    const float* xyz           = (const float*)d_in[1];
    const int*   xyz_batch_cnt = (const int*)d_in[2];
    const float* new_xyz       = (const float*)d_in[3];
    // d_in[4] = new_xyz_batch_cnt (unused)
    const float* features      = (const float*)d_in[5];
    const int*   v2p           = (const int*)d_in[6];

    const int M = in_sizes[0] / 4;

    float* out_feat  = (float*)d_out;                       // M*CF*NS
    float* out_xyz   = out_feat + (size_t)M * CF * NS;      // M*3*NS
    float* out_empty = out_xyz + (size_t)M * 3 * NS;        // M

    const int blocks = (M + 3) / 4;
    vqg_kernel<<<blocks, 256, 0, stream>>>(
        new_coords, xyz, xyz_batch_cnt, new_xyz, features, v2p,
        out_feat, out_xyz, out_empty, M);
}